// Round 6
// baseline (282.824 us; speedup 1.0000x reference)
//
#include <hip/hip_runtime.h>
#include <hip/hip_cooperative_groups.h>

#define N 8192

namespace cg = cooperative_groups;

typedef float f32x4 __attribute__((ext_vector_type(4)));

// ===================== fused cooperative single-pass =====================
// 1024 blocks x 256 threads, 4 blocks/CU co-resident. Each block owns 8 rows.
// Phase 1: read A once (nt), exact fp32 row sums, quantize u8 into 32 regs +
// 32 LDS words per lane (on-chip shadow; never hits HBM).
// grid.sync(). Phase 2: dequant, scale by dinv_i*dinv_j, nt-store out.
// Traffic: 268 MB A-read + 268 MB out-write = 536 MB (vs 670 two-pass).
__global__ __launch_bounds__(256, 4) void fused_kernel(const float* __restrict__ A,
                                                       float* __restrict__ dinv,
                                                       float* __restrict__ out) {
    __shared__ unsigned int qlds[8192];            // 32 KiB: [(wrow)*16 + (k-16)]*64 + lane

    const int wave = threadIdx.x >> 6;
    const int lane = threadIdx.x & 63;
    const int row0 = blockIdx.x * 8;               // 8 rows per block, 2 per wave

    unsigned int qreg[2][16];                      // 32 u32 payload regs/lane

    // ---- phase 1 ----
#pragma unroll
    for (int r = 0; r < 2; ++r) {
        const int wrow = wave * 2 + r;
        const int row  = row0 + wrow;
        const f32x4* arow = reinterpret_cast<const f32x4*>(A + (size_t)row * N);

        float s = 0.0f;
#pragma unroll
        for (int k = 0; k < 32; ++k) {
            f32x4 v = __builtin_nontemporal_load(&arow[k * 64 + lane]);
            s += (v.x + v.y) + (v.z + v.w);
            unsigned int b0 = __float2uint_rn(v.x * 255.0f);
            unsigned int b1 = __float2uint_rn(v.y * 255.0f);
            unsigned int b2 = __float2uint_rn(v.z * 255.0f);
            unsigned int b3 = __float2uint_rn(v.w * 255.0f);
            unsigned int b  = b0 | (b1 << 8) | (b2 << 16) | (b3 << 24);
            if (k < 16) qreg[r][k] = b;                       // k compile-time: static index
            else        qlds[(wrow * 16 + (k - 16)) * 64 + lane] = b;  // stride-1: conflict-free
        }

#pragma unroll
        for (int off = 32; off >= 1; off >>= 1)
            s += __shfl_xor(s, off, 64);
        if (lane == 0)
            dinv[row] = 1.0f / sqrtf(s);
    }

    cg::this_grid().sync();                        // device-scope fence + grid barrier

    // ---- phase 2 ----
    const f32x4* d4 = reinterpret_cast<const f32x4*>(dinv);

#pragma unroll
    for (int r = 0; r < 2; ++r) {
        const int wrow = wave * 2 + r;
        const int row  = row0 + wrow;
        const float ris = dinv[row] * (1.0f / 255.0f);   // broadcast load, fold dequant
        f32x4* orow = reinterpret_cast<f32x4*>(out + (size_t)row * N);

#pragma unroll
        for (int k = 0; k < 32; ++k) {
            const unsigned int b = (k < 16) ? qreg[r][k]
                                            : qlds[(wrow * 16 + (k - 16)) * 64 + lane];
            f32x4 f;                                      // v_cvt_f32_ubyte0..3
            f.x = (float)(b & 0xffu);
            f.y = (float)((b >> 8) & 0xffu);
            f.z = (float)((b >> 16) & 0xffu);
            f.w = (float)(b >> 24);
            f32x4 c = d4[k * 64 + lane];                 // 32 KB, L1-hot
            __builtin_nontemporal_store(f * ris * c, &orow[k * 64 + lane]);
        }
    }
}

// ===================== fallback: proven R5 two-pass (108 µs) =====================

__global__ __launch_bounds__(256) void rowsum_quant_kernel(const float* __restrict__ A,
                                                           float* __restrict__ dinv,
                                                           unsigned int* __restrict__ q) {
    const int wave = threadIdx.x >> 6;
    const int lane = threadIdx.x & 63;
    const int row  = blockIdx.x * 4 + wave;

    const f32x4*  arow = reinterpret_cast<const f32x4*>(A + (size_t)row * N);
    unsigned int* qrow = q + (size_t)row * (N / 4);

    float s = 0.0f;
#pragma unroll
    for (int k = 0; k < 32; ++k) {
        const int idx = k * 64 + lane;
        f32x4 v = __builtin_nontemporal_load(&arow[idx]);
        s += (v.x + v.y) + (v.z + v.w);
        unsigned int b0 = __float2uint_rn(v.x * 255.0f);
        unsigned int b1 = __float2uint_rn(v.y * 255.0f);
        unsigned int b2 = __float2uint_rn(v.z * 255.0f);
        unsigned int b3 = __float2uint_rn(v.w * 255.0f);
        qrow[idx] = b0 | (b1 << 8) | (b2 << 16) | (b3 << 24);
    }
#pragma unroll
    for (int off = 32; off >= 1; off >>= 1)
        s += __shfl_xor(s, off, 64);
    if (lane == 0)
        dinv[row] = 1.0f / sqrtf(s);
}

__global__ __launch_bounds__(256) void scale_q_kernel(const unsigned int* __restrict__ q,
                                                      const float* __restrict__ dinv,
                                                      float* __restrict__ out) {
    const int row = (N - 1) - blockIdx.x;
    const float ris = dinv[row] * (1.0f / 255.0f);

    const unsigned int* qrow = q + (size_t)row * (N / 4);
    const f32x4* d4 = reinterpret_cast<const f32x4*>(dinv);
    f32x4*       o4 = reinterpret_cast<f32x4*>(out + (size_t)row * N);

#pragma unroll
    for (int k = 0; k < 8; ++k) {
        const int idx = k * 256 + threadIdx.x;
        const unsigned int b = qrow[idx];
        f32x4 f;
        f.x = (float)(b & 0xffu);
        f.y = (float)((b >> 8) & 0xffu);
        f.z = (float)((b >> 16) & 0xffu);
        f.w = (float)(b >> 24);
        __builtin_nontemporal_store(f * ris * d4[idx], &o4[idx]);
    }
}

extern "C" void kernel_launch(void* const* d_in, const int* in_sizes, int n_in,
                              void* d_out, int out_size, void* d_ws, size_t ws_size,
                              hipStream_t stream) {
    const float* A    = (const float*)d_in[0];
    float*       out  = (float*)d_out;
    float*       dinv = (float*)d_ws;                   // 32 KB

    // Try fused cooperative single-pass
    void* args[] = {(void*)&A, (void*)&dinv, (void*)&out};
    hipError_t err = hipLaunchCooperativeKernel((const void*)fused_kernel,
                                                dim3(N / 8), dim3(256),
                                                args, 0, stream);
    if (err == hipSuccess) return;

    // Fallback: two-pass u8-shadow (needs 64 MiB + dinv in ws)
    const size_t need = (size_t)N * 4 + (size_t)N * N;
    if (ws_size >= need) {
        unsigned int* q = (unsigned int*)((char*)d_ws + (size_t)N * 4);
        rowsum_quant_kernel<<<N / 4, 256, 0, stream>>>(A, dinv, q);
        scale_q_kernel<<<N, 256, 0, stream>>>(q, dinv, out);
    }
}

// Round 7
// 262.133 us; speedup vs baseline: 1.0789x; 1.0789x over previous
//
#include <hip/hip_runtime.h>
#include <hip/hip_cooperative_groups.h>

#define N 8192

namespace cg = cooperative_groups;

typedef float f32x4 __attribute__((ext_vector_type(4)));

#define RPB 8     // rows per block (2 per wave)
#define KL  20    // k-slots (of 32) kept in LDS per row -> 40960 B/block
                  // slots KL..31 (12) kept in 3 named uint4 per row per lane

__device__ __forceinline__ unsigned int qpack(f32x4 v, float& s) {
    s += (v.x + v.y) + (v.z + v.w);
    unsigned int b0 = __float2uint_rn(v.x * 255.0f);
    unsigned int b1 = __float2uint_rn(v.y * 255.0f);
    unsigned int b2 = __float2uint_rn(v.z * 255.0f);
    unsigned int b3 = __float2uint_rn(v.w * 255.0f);
    return b0 | (b1 << 8) | (b2 << 16) | (b3 << 24);
}

__device__ __forceinline__ void emit(unsigned int b, float ris,
                                     const f32x4* __restrict__ c4, f32x4* __restrict__ o) {
    f32x4 f;                       // v_cvt_f32_ubyte0..3
    f.x = (float)(b & 0xffu);
    f.y = (float)((b >> 8) & 0xffu);
    f.z = (float)((b >> 16) & 0xffu);
    f.w = (float)(b >> 24);
    __builtin_nontemporal_store(f * ris * (*c4), o);
}

// ===================== fused cooperative single-pass (v2, spill-proof) =====
// 1024 blocks x 256 threads, 4 blocks/CU (LDS-limited: 4 x 40960 B = 160 KiB).
// Phase 1: read A once (nt), exact fp32 row sums, u8 shadow entirely ON-CHIP:
// 20/32 slots in LDS, 12/32 in named uint4 regs (straight-line, never demoted).
// grid.sync(). Phase 2: dequant, scale dinv_i*dinv_j, nt-store out.
// HBM traffic: 268 MB A-read + 268 MB out-write. Shadow never touches HBM.
__global__ __launch_bounds__(256, 4) void fused_kernel(const float* __restrict__ A,
                                                       float* __restrict__ dinv,
                                                       float* __restrict__ out) {
    __shared__ unsigned int qlds[RPB * KL * 64];   // 40960 B

    const int wave = threadIdx.x >> 6;
    const int lane = threadIdx.x & 63;
    const int row0 = blockIdx.x * RPB;

    uint4 q00, q01, q02;   // row (wave*2+0), slots 20..31
    uint4 q10, q11, q12;   // row (wave*2+1), slots 20..31

    // ---- phase 1: rowsum + quantize ----
#define P1_ROW(R, Q0, Q1, Q2)                                                   \
    {                                                                           \
        const int wrow = wave * 2 + (R);                                        \
        const int row  = row0 + wrow;                                           \
        const f32x4* arow = reinterpret_cast<const f32x4*>(A + (size_t)row * N);\
        float s = 0.0f;                                                         \
        _Pragma("unroll")                                                       \
        for (int k = 0; k < KL; ++k) {                                          \
            f32x4 v = __builtin_nontemporal_load(&arow[k * 64 + lane]);         \
            qlds[(wrow * KL + k) * 64 + lane] = qpack(v, s);                    \
        }                                                                       \
        Q0.x = qpack(__builtin_nontemporal_load(&arow[(KL + 0) * 64 + lane]), s); \
        Q0.y = qpack(__builtin_nontemporal_load(&arow[(KL + 1) * 64 + lane]), s); \
        Q0.z = qpack(__builtin_nontemporal_load(&arow[(KL + 2) * 64 + lane]), s); \
        Q0.w = qpack(__builtin_nontemporal_load(&arow[(KL + 3) * 64 + lane]), s); \
        Q1.x = qpack(__builtin_nontemporal_load(&arow[(KL + 4) * 64 + lane]), s); \
        Q1.y = qpack(__builtin_nontemporal_load(&arow[(KL + 5) * 64 + lane]), s); \
        Q1.z = qpack(__builtin_nontemporal_load(&arow[(KL + 6) * 64 + lane]), s); \
        Q1.w = qpack(__builtin_nontemporal_load(&arow[(KL + 7) * 64 + lane]), s); \
        Q2.x = qpack(__builtin_nontemporal_load(&arow[(KL + 8) * 64 + lane]), s); \
        Q2.y = qpack(__builtin_nontemporal_load(&arow[(KL + 9) * 64 + lane]), s); \
        Q2.z = qpack(__builtin_nontemporal_load(&arow[(KL +10) * 64 + lane]), s); \
        Q2.w = qpack(__builtin_nontemporal_load(&arow[(KL +11) * 64 + lane]), s); \
        _Pragma("unroll")                                                       \
        for (int off = 32; off >= 1; off >>= 1) s += __shfl_xor(s, off, 64);    \
        if (lane == 0) dinv[row] = 1.0f / sqrtf(s);                             \
    }

    P1_ROW(0, q00, q01, q02)
    P1_ROW(1, q10, q11, q12)
#undef P1_ROW

    cg::this_grid().sync();   // all row sums visible device-wide

    // ---- phase 2: dequant + scale + store ----
    const f32x4* d4 = reinterpret_cast<const f32x4*>(dinv);

#define P2_ROW(R, Q0, Q1, Q2)                                                   \
    {                                                                           \
        const int wrow = wave * 2 + (R);                                        \
        const int row  = row0 + wrow;                                           \
        const float ris = dinv[row] * (1.0f / 255.0f);                          \
        f32x4* orow = reinterpret_cast<f32x4*>(out + (size_t)row * N);          \
        _Pragma("unroll")                                                       \
        for (int k = 0; k < KL; ++k)                                            \
            emit(qlds[(wrow * KL + k) * 64 + lane], ris,                        \
                 &d4[k * 64 + lane], &orow[k * 64 + lane]);                     \
        emit(Q0.x, ris, &d4[(KL + 0) * 64 + lane], &orow[(KL + 0) * 64 + lane]); \
        emit(Q0.y, ris, &d4[(KL + 1) * 64 + lane], &orow[(KL + 1) * 64 + lane]); \
        emit(Q0.z, ris, &d4[(KL + 2) * 64 + lane], &orow[(KL + 2) * 64 + lane]); \
        emit(Q0.w, ris, &d4[(KL + 3) * 64 + lane], &orow[(KL + 3) * 64 + lane]); \
        emit(Q1.x, ris, &d4[(KL + 4) * 64 + lane], &orow[(KL + 4) * 64 + lane]); \
        emit(Q1.y, ris, &d4[(KL + 5) * 64 + lane], &orow[(KL + 5) * 64 + lane]); \
        emit(Q1.z, ris, &d4[(KL + 6) * 64 + lane], &orow[(KL + 6) * 64 + lane]); \
        emit(Q1.w, ris, &d4[(KL + 7) * 64 + lane], &orow[(KL + 7) * 64 + lane]); \
        emit(Q2.x, ris, &d4[(KL + 8) * 64 + lane], &orow[(KL + 8) * 64 + lane]); \
        emit(Q2.y, ris, &d4[(KL + 9) * 64 + lane], &orow[(KL + 9) * 64 + lane]); \
        emit(Q2.z, ris, &d4[(KL +10) * 64 + lane], &orow[(KL +10) * 64 + lane]); \
        emit(Q2.w, ris, &d4[(KL +11) * 64 + lane], &orow[(KL +11) * 64 + lane]); \
    }

    P2_ROW(0, q00, q01, q02)
    P2_ROW(1, q10, q11, q12)
#undef P2_ROW
}

// ===================== fallback: proven R5 two-pass (108 µs) =====================

__global__ __launch_bounds__(256) void rowsum_quant_kernel(const float* __restrict__ A,
                                                           float* __restrict__ dinv,
                                                           unsigned int* __restrict__ q) {
    const int wave = threadIdx.x >> 6;
    const int lane = threadIdx.x & 63;
    const int row  = blockIdx.x * 4 + wave;

    const f32x4*  arow = reinterpret_cast<const f32x4*>(A + (size_t)row * N);
    unsigned int* qrow = q + (size_t)row * (N / 4);

    float s = 0.0f;
#pragma unroll
    for (int k = 0; k < 32; ++k) {
        const int idx = k * 64 + lane;
        f32x4 v = __builtin_nontemporal_load(&arow[idx]);
        qrow[idx] = qpack(v, s);
    }
#pragma unroll
    for (int off = 32; off >= 1; off >>= 1)
        s += __shfl_xor(s, off, 64);
    if (lane == 0)
        dinv[row] = 1.0f / sqrtf(s);
}

__global__ __launch_bounds__(256) void scale_q_kernel(const unsigned int* __restrict__ q,
                                                      const float* __restrict__ dinv,
                                                      float* __restrict__ out) {
    const int row = (N - 1) - blockIdx.x;
    const float ris = dinv[row] * (1.0f / 255.0f);

    const unsigned int* qrow = q + (size_t)row * (N / 4);
    const f32x4* d4 = reinterpret_cast<const f32x4*>(dinv);
    f32x4*       o4 = reinterpret_cast<f32x4*>(out + (size_t)row * N);

#pragma unroll
    for (int k = 0; k < 8; ++k) {
        const int idx = k * 256 + threadIdx.x;
        emit(qrow[idx], ris, &d4[idx], &o4[idx]);
    }
}

extern "C" void kernel_launch(void* const* d_in, const int* in_sizes, int n_in,
                              void* d_out, int out_size, void* d_ws, size_t ws_size,
                              hipStream_t stream) {
    const float* A    = (const float*)d_in[0];
    float*       out  = (float*)d_out;
    float*       dinv = (float*)d_ws;                   // 32 KB

    void* args[] = {(void*)&A, (void*)&dinv, (void*)&out};
    hipError_t err = hipLaunchCooperativeKernel((const void*)fused_kernel,
                                                dim3(N / RPB), dim3(256),
                                                args, 0, stream);
    if (err == hipSuccess) return;

    // Fallback: two-pass u8-shadow (needs 64 MiB + dinv in ws)
    const size_t need = (size_t)N * 4 + (size_t)N * N;
    if (ws_size >= need) {
        unsigned int* q = (unsigned int*)((char*)d_ws + (size_t)N * 4);
        rowsum_quant_kernel<<<N / 4, 256, 0, stream>>>(A, dinv, q);
        scale_q_kernel<<<N, 256, 0, stream>>>(q, dinv, out);
    }
}